// Round 1
// baseline (700.982 us; speedup 1.0000x reference)
//
#include <hip/hip_runtime.h>
#include <cstdint>

// ---------- types ----------
typedef float f32x4 __attribute__((ext_vector_type(4)));
typedef __bf16 bf16x8 __attribute__((ext_vector_type(8)));

#define AS1 __attribute__((address_space(1)))
#define AS3 __attribute__((address_space(3)))

__device__ __forceinline__ void gld_lds16(const void* g, void* l) {
    // async global->LDS, 16B per lane; LDS dest = wave-uniform base + lane*16
    __builtin_amdgcn_global_load_lds((const AS1 void*)g, (AS3 void*)l, 16, 0, 0);
}

__device__ __forceinline__ unsigned short f2bf(float f) {  // RNE f32->bf16
    unsigned u = __builtin_bit_cast(unsigned, f);
    u = u + 0x7fffu + ((u >> 16) & 1u);
    return (unsigned short)(u >> 16);
}
__device__ __forceinline__ float bf2f(unsigned short h) {
    unsigned u = ((unsigned)h) << 16;
    return __builtin_bit_cast(float, u);
}

// ---------- GEMM: C = A @ B^T, A[M][K], B[N][K], bf16 in, f32 accum ----------
// MODE 0: C f32 = acc                  (S matrix)
// MODE 1: C f32 = acc + add            (PV + residual -> x1)
// MODE 2: C bf16 = gelu(acc + bias)    (MLP hidden)
// MODE 3: C f32 = acc + bias + add     (MLP out + residual)
template<int MODE>
__global__ __launch_bounds__(256) void gemm_nt(
    const unsigned short* __restrict__ A, long lda, long sAb,
    const unsigned short* __restrict__ B, long ldb, long sBb,
    void* C, long ldc, long sCb,
    const float* add, long ldadd, long sAddb,
    const float* __restrict__ bias,
    int K)
{
    __shared__ char smA[128 * 64 * 2];   // 16 KB, rows of 128B
    __shared__ char smB[128 * 64 * 2];
    const int tid  = threadIdx.x;
    const int lane = tid & 63, wid = tid >> 6;
    const int wr = wid >> 1, wc = wid & 1;          // 2x2 wave grid, 64x64 each
    const long zb = blockIdx.z;
    const char* Ab = (const char*)(A + zb * sAb + (long)blockIdx.y * 128 * lda);
    const char* Bb = (const char*)(B + zb * sBb + (long)blockIdx.x * 128 * ldb);
    const long lda2 = lda * 2, ldb2 = ldb * 2;
    const int srow = lane >> 3;            // 8 lanes per 128B row
    const int scol = (lane & 7) * 16;      // byte col within row

    f32x4 acc[4][4] = {};
    for (int k0 = 0; k0 < K; k0 += 64) {
        if (k0) __syncthreads();           // protect LDS being read
        const long kb = (long)k0 * 2;
#pragma unroll
        for (int i = 0; i < 4; ++i) {
            const int seg = i * 4 + wid;   // 16 segments of 1KB (8 rows)
            const int r = seg * 8 + srow;
            gld_lds16(Ab + (long)r * lda2 + kb + scol, smA + seg * 1024);
            gld_lds16(Bb + (long)r * ldb2 + kb + scol, smB + seg * 1024);
        }
        __syncthreads();                   // vmcnt(0) drain + barrier
#pragma unroll
        for (int kk = 0; kk < 2; ++kk) {
            bf16x8 af[4], bfm[4];
#pragma unroll
            for (int m = 0; m < 4; ++m)
                af[m] = *(const bf16x8*)(smA + (wr * 64 + m * 16 + (lane & 15)) * 128 + kk * 64 + (lane >> 4) * 16);
#pragma unroll
            for (int n = 0; n < 4; ++n)
                bfm[n] = *(const bf16x8*)(smB + (wc * 64 + n * 16 + (lane & 15)) * 128 + kk * 64 + (lane >> 4) * 16);
#pragma unroll
            for (int m = 0; m < 4; ++m)
#pragma unroll
                for (int n = 0; n < 4; ++n)
                    acc[m][n] = __builtin_amdgcn_mfma_f32_16x16x32_bf16(af[m], bfm[n], acc[m][n], 0, 0, 0);
        }
    }
    // epilogue: C/D layout col=lane&15, row=(lane>>4)*4+j
    const long row0 = (long)blockIdx.y * 128 + wr * 64 + (lane >> 4) * 4;
    const long col0 = (long)blockIdx.x * 128 + wc * 64 + (lane & 15);
#pragma unroll
    for (int m = 0; m < 4; ++m)
#pragma unroll
        for (int n = 0; n < 4; ++n)
#pragma unroll
            for (int j = 0; j < 4; ++j) {
                const long r = row0 + m * 16 + j;
                const long c = col0 + n * 16;
                const float v = acc[m][n][j];
                if (MODE == 0) {
                    ((float*)C)[zb * sCb + r * ldc + c] = v;
                } else if (MODE == 1) {
                    ((float*)C)[zb * sCb + r * ldc + c] = v + add[zb * sAddb + r * ldadd + c];
                } else if (MODE == 2) {
                    float t = v + bias[c];
                    float gl = 0.5f * t * (1.0f + erff(t * 0.70710678118654752f));
                    ((unsigned short*)C)[zb * sCb + r * ldc + c] = f2bf(gl);
                } else {
                    ((float*)C)[zb * sCb + r * ldc + c] = v + bias[c] + add[zb * sAddb + r * ldadd + c];
                }
            }
}

// ---------- LayerNorm: f32 in -> bf16 out (+ optional sum(y^2), + zero pad) ----------
__global__ __launch_bounds__(256) void ln_kernel(
    const float* __restrict__ x, const float* __restrict__ gamma, const float* __restrict__ beta,
    unsigned short* __restrict__ out, int ldout, float* qout, int pad)
{
    const int tid = threadIdx.x;
    const long row = blockIdx.x;
    float4 v = ((const float4*)(x + row * 1024))[tid];
    float s = v.x + v.y + v.z + v.w;
    float s2 = v.x * v.x + v.y * v.y + v.z * v.z + v.w * v.w;
#pragma unroll
    for (int off = 32; off; off >>= 1) {
        s  += __shfl_down(s, off);
        s2 += __shfl_down(s2, off);
    }
    __shared__ float red[12];
    const int lane = tid & 63, wid = tid >> 6;
    if (lane == 0) { red[wid] = s; red[4 + wid] = s2; }
    __syncthreads();
    s  = red[0] + red[1] + red[2] + red[3];
    s2 = red[4] + red[5] + red[6] + red[7];
    const float mu = s * (1.0f / 1024.0f);
    const float var = s2 * (1.0f / 1024.0f) - mu * mu;
    const float rs = rsqrtf(var + 1e-5f);
    const float4 g = ((const float4*)gamma)[tid];
    const float4 b = ((const float4*)beta)[tid];
    unsigned short o0 = f2bf((v.x - mu) * rs * g.x + b.x);
    unsigned short o1 = f2bf((v.y - mu) * rs * g.y + b.y);
    unsigned short o2 = f2bf((v.z - mu) * rs * g.z + b.z);
    unsigned short o3 = f2bf((v.w - mu) * rs * g.w + b.w);
    ushort4 ov; ov.x = o0; ov.y = o1; ov.z = o2; ov.w = o3;
    ((ushort4*)(out + row * (long)ldout))[tid] = ov;
    if (pad && tid < 32) out[row * (long)ldout + 1056 + tid] = 0;  // zero K-pad
    if (qout) {  // q partial = sum over d of (rounded hn)^2
        float y0 = bf2f(o0), y1 = bf2f(o1), y2 = bf2f(o2), y3 = bf2f(o3);
        float sq = y0 * y0 + y1 * y1 + y2 * y2 + y3 * y3;
#pragma unroll
        for (int off = 32; off; off >>= 1) sq += __shfl_down(sq, off);
        if (lane == 0) red[8 + wid] = sq;
        __syncthreads();
        if (tid == 0) qout[row] = red[8] + red[9] + red[10] + red[11];
    }
}

// ---------- u = hn @ L (r=32), write bf16 into z cols [1024,1056), q += |u|^2 ----------
__global__ __launch_bounds__(256) void u_kernel(
    unsigned short* __restrict__ z, const float* __restrict__ L, float* __restrict__ q)
{
    const int tid = threadIdx.x;
    const long row = blockIdx.x;
    __shared__ float hn[1024];
    __shared__ float part[8][32];
    ushort4 uv = ((const ushort4*)(z + row * 1088))[tid];
    hn[tid * 4 + 0] = bf2f(uv.x);
    hn[tid * 4 + 1] = bf2f(uv.y);
    hn[tid * 4 + 2] = bf2f(uv.z);
    hn[tid * 4 + 3] = bf2f(uv.w);
    __syncthreads();
    const int j = tid & 31, grp = tid >> 5;
    float acc = 0.f;
    const float* Lp = L + j;
#pragma unroll 4
    for (int d = grp * 128; d < grp * 128 + 128; ++d)
        acc += hn[d] * Lp[(long)d * 32];
    part[grp][j] = acc;
    __syncthreads();
    if (tid < 32) {
        float u = 0.f;
#pragma unroll
        for (int g2 = 0; g2 < 8; ++g2) u += part[g2][tid];
        unsigned short ub = f2bf(u);
        z[row * 1088 + 1024 + tid] = ub;
        float uf = bf2f(ub);
        part[0][tid] = uf * uf;
    }
    __syncthreads();
    if (tid == 0) {
        float sq = 0.f;
#pragma unroll
        for (int t2 = 0; t2 < 32; ++t2) sq += part[0][t2];
        q[row] += sq;
    }
}

// ---------- softmax over row: logits = 2*S - q_j; write P bf16 in place ----------
__global__ __launch_bounds__(256) void softmax_kernel(
    float* S, const float* qb)
{
    const int tid = threadIdx.x;
    const long i = blockIdx.x, bl = blockIdx.y;
    float* Sr = S + (bl * 2048 + i) * 2048;
    const float* qr = qb + bl * 2048;
    float l[8];
    float mx = -1e30f;
#pragma unroll
    for (int c2 = 0; c2 < 8; ++c2) {
        const int jj = tid + c2 * 256;
        l[c2] = 2.0f * Sr[jj] - qr[jj];
        mx = fmaxf(mx, l[c2]);
    }
#pragma unroll
    for (int off = 32; off; off >>= 1) mx = fmaxf(mx, __shfl_xor(mx, off));
    __shared__ float red[8];
    const int lane = tid & 63, wid = tid >> 6;
    if (lane == 0) red[wid] = mx;
    __syncthreads();
    mx = fmaxf(fmaxf(red[0], red[1]), fmaxf(red[2], red[3]));
    float sum = 0.f;
#pragma unroll
    for (int c2 = 0; c2 < 8; ++c2) { l[c2] = __expf(l[c2] - mx); sum += l[c2]; }
#pragma unroll
    for (int off = 32; off; off >>= 1) sum += __shfl_xor(sum, off);
    if (lane == 0) red[4 + wid] = sum;
    __syncthreads();
    sum = red[4] + red[5] + red[6] + red[7];
    const float inv = 1.0f / sum;
    unsigned short* Pr = (unsigned short*)S + (bl * 2048 + i) * 4096;  // row stride 8192B
#pragma unroll
    for (int c2 = 0; c2 < 8; ++c2)
        Pr[tid + c2 * 256] = f2bf(l[c2] * inv);
}

// ---------- Vt[b][n][k] = z[b][k][n] (hn part only), bf16 ----------
__global__ __launch_bounds__(256) void transpose_v_kernel(
    const unsigned short* __restrict__ z, unsigned short* __restrict__ Vt, long sVtb)
{
    __shared__ unsigned short t[32][33];
    const int tid = threadIdx.x;
    const int tx = tid & 31, ty = tid >> 5;
    const long b = blockIdx.z;
    const long k0 = (long)blockIdx.x * 32, n0 = (long)blockIdx.y * 32;
#pragma unroll
    for (int r = 0; r < 32; r += 8)
        t[r + ty][tx] = z[(b * 2048 + k0 + r + ty) * 1088 + n0 + tx];
    __syncthreads();
#pragma unroll
    for (int r = 0; r < 32; r += 8)
        Vt[b * sVtb + (n0 + r + ty) * 2048 + k0 + tx] = t[tx][r + ty];
}

// ---------- Wt[c][r] = bf16(W[r][c]) ----------
__global__ __launch_bounds__(256) void cast_transpose_kernel(
    const float* __restrict__ W, unsigned short* __restrict__ Wt, int rows, int cols)
{
    __shared__ float t[32][33];
    const int tid = threadIdx.x;
    const int tx = tid & 31, ty = tid >> 5;
    const long r0 = (long)blockIdx.y * 32, c0 = (long)blockIdx.x * 32;
#pragma unroll
    for (int r = 0; r < 32; r += 8)
        t[r + ty][tx] = W[(r0 + r + ty) * (long)cols + c0 + tx];
    __syncthreads();
#pragma unroll
    for (int r = 0; r < 32; r += 8)
        Wt[(c0 + r + ty) * (long)rows + r0 + tx] = f2bf(t[tx][r + ty]);
}

// ---------- host ----------
extern "C" void kernel_launch(void* const* d_in, const int* in_sizes, int n_in,
                              void* d_out, int out_size, void* d_ws, size_t ws_size,
                              hipStream_t stream)
{
    const float* x   = (const float*)d_in[0];
    const float* L   = (const float*)d_in[1];
    const float* W1  = (const float*)d_in[2];
    const float* b1  = (const float*)d_in[3];
    const float* W2  = (const float*)d_in[4];
    const float* b2  = (const float*)d_in[5];
    const float* g1  = (const float*)d_in[6];
    const float* be1 = (const float*)d_in[7];
    const float* g2  = (const float*)d_in[8];
    const float* be2 = (const float*)d_in[9];
    float* out = (float*)d_out;

    char* w = (char*)d_ws;
    auto alloc = [&](size_t sz) { char* p = w; w += (sz + 255) & ~(size_t)255; return p; };
    unsigned short* z   = (unsigned short*)alloc((size_t)8192 * 1088 * 2);  // [hn | u | 0pad]
    float*          q   = (float*)alloc((size_t)8192 * 4);
    unsigned short* hm  = (unsigned short*)alloc((size_t)8192 * 1024 * 2);
    unsigned short* W1t = (unsigned short*)alloc((size_t)4096 * 1024 * 2);
    unsigned short* W2t = (unsigned short*)alloc((size_t)1024 * 4096 * 2);
    unsigned short* hid = (unsigned short*)alloc((size_t)2048 * 4096 * 2);  // M-chunked
    size_t used = (size_t)(w - (char*)d_ws);
    size_t per_batch = ((size_t)1024 * 2048 * 2 + 256) + ((size_t)2048 * 2048 * 4 + 256);
    int nbp = (ws_size > used && (ws_size - used) >= 4 * per_batch) ? 4 : 1;
    unsigned short* Vt   = (unsigned short*)alloc((size_t)nbp * 1024 * 2048 * 2);
    float*          Smat = (float*)alloc((size_t)nbp * 2048 * 2048 * 4);

    // weight casts (transposed to N-major for NT GEMM)
    cast_transpose_kernel<<<dim3(128, 32), 256, 0, stream>>>(W1, W1t, 1024, 4096);
    cast_transpose_kernel<<<dim3(32, 128), 256, 0, stream>>>(W2, W2t, 4096, 1024);
    // LN1 -> z[:,0:1024], q = |hn|^2, zero pad cols 1056:1088
    ln_kernel<<<8192, 256, 0, stream>>>(x, g1, be1, z, 1088, q, 1);
    // u = hn@L -> z[:,1024:1056], q += |u|^2
    u_kernel<<<8192, 256, 0, stream>>>(z, L, q);

    // attention (batch-parallel if ws allows, else per-batch)
    for (int b = 0; b < 4; b += nbp) {
        const unsigned short* zb = z + (size_t)b * 2048 * 1088;
        transpose_v_kernel<<<dim3(64, 32, nbp), 256, 0, stream>>>(zb, Vt, (long)1024 * 2048);
        gemm_nt<0><<<dim3(16, 16, nbp), 256, 0, stream>>>(
            zb, 1088, (long)2048 * 1088,
            zb, 1088, (long)2048 * 1088,
            Smat, 2048, (long)2048 * 2048,
            nullptr, 0, 0, nullptr, 1088);
        softmax_kernel<<<dim3(2048, nbp), 256, 0, stream>>>(Smat, q + (size_t)b * 2048);
        gemm_nt<1><<<dim3(8, 16, nbp), 256, 0, stream>>>(
            (const unsigned short*)Smat, 4096, (long)2048 * 4096,
            Vt, 2048, (long)1024 * 2048,
            out + (size_t)b * 2048 * 1024, 1024, (long)2048 * 1024,
            x + (size_t)b * 2048 * 1024, 1024, (long)2048 * 1024,
            nullptr, 2048);
    }

    // LN2 on x1 (stored in d_out)
    ln_kernel<<<8192, 256, 0, stream>>>(out, g2, be2, hm, 1024, nullptr, 0);
    // MLP, M-chunked by 2048 rows
    for (int c = 0; c < 4; ++c) {
        const unsigned short* hmc = hm + (size_t)c * 2048 * 1024;
        float* oc = out + (size_t)c * 2048 * 1024;
        gemm_nt<2><<<dim3(32, 16, 1), 256, 0, stream>>>(
            hmc, 1024, 0, W1t, 1024, 0,
            hid, 4096, 0, nullptr, 0, 0, b1, 1024);
        gemm_nt<3><<<dim3(8, 16, 1), 256, 0, stream>>>(
            hid, 4096, 0, W2t, 4096, 0,
            oc, 1024, 0, oc, 1024, 0, b2, 4096);
    }
}

// Round 2
// 425.062 us; speedup vs baseline: 1.6491x; 1.6491x over previous
//
#include <hip/hip_runtime.h>
#include <cstdint>

// ---------- types ----------
typedef float f32x4 __attribute__((ext_vector_type(4)));
typedef __bf16 bf16x8 __attribute__((ext_vector_type(8)));

#define AS1 __attribute__((address_space(1)))
#define AS3 __attribute__((address_space(3)))

__device__ __forceinline__ void gld_lds16(const void* g, void* l) {
    // async global->LDS, 16B per lane; LDS dest = wave-uniform base + lane*16
    __builtin_amdgcn_global_load_lds((const AS1 void*)g, (AS3 void*)l, 16, 0, 0);
}

__device__ __forceinline__ unsigned short f2bf(float f) {  // RNE f32->bf16
    unsigned u = __builtin_bit_cast(unsigned, f);
    u = u + 0x7fffu + ((u >> 16) & 1u);
    return (unsigned short)(u >> 16);
}
__device__ __forceinline__ float bf2f(unsigned short h) {
    unsigned u = ((unsigned)h) << 16;
    return __builtin_bit_cast(float, u);
}

// ---------- GEMM: C = A @ B^T, A[M][K], B[N][K], bf16 in, f32 accum ----------
// MODE 0: C f32 = acc                  (S matrix)
// MODE 1: C f32 = acc + add            (PV + residual -> x1)
// MODE 2: C bf16 = gelu(acc + bias)    (MLP hidden)
// MODE 3: C f32 = acc + bias + add     (MLP out + residual)
template<int MODE>
__global__ __launch_bounds__(256) void gemm_nt(
    const unsigned short* __restrict__ A, long lda, long sAb,
    const unsigned short* __restrict__ B, long ldb, long sBb,
    void* C, long ldc, long sCb,
    const float* add, long ldadd, long sAddb,
    const float* __restrict__ bias,
    int K)
{
    __shared__ char smA[128 * 64 * 2];   // 16 KB, rows of 128B
    __shared__ char smB[128 * 64 * 2];
    const int tid  = threadIdx.x;
    const int lane = tid & 63, wid = tid >> 6;
    const int wr = wid >> 1, wc = wid & 1;          // 2x2 wave grid, 64x64 each
    const long zb = blockIdx.z;

    // T1: bijective XCD-aware swizzle (m204) within the z-slice
    const int nwg  = gridDim.x * gridDim.y;
    const int orig = blockIdx.y * gridDim.x + blockIdx.x;
    const int q8 = nwg >> 3, r8 = nwg & 7;
    const int xcd = orig & 7;
    const int wg  = (xcd < r8 ? xcd * (q8 + 1) : r8 * (q8 + 1) + (xcd - r8) * q8) + (orig >> 3);
    const int bx = wg % gridDim.x, by = wg / gridDim.x;

    const char* Ab = (const char*)(A + zb * sAb + (long)by * 128 * lda);
    const char* Bb = (const char*)(B + zb * sBb + (long)bx * 128 * ldb);
    const long lda2 = lda * 2, ldb2 = ldb * 2;
    const int srow = lane >> 3;            // 8 lanes per 128B row
    const int scol = (lane & 7) * 16;      // byte col within row

    f32x4 acc[4][4] = {};
    for (int k0 = 0; k0 < K; k0 += 64) {
        if (k0) __syncthreads();           // protect LDS being read
        const long kb = (long)k0 * 2;
#pragma unroll
        for (int i = 0; i < 4; ++i) {
            const int seg = i * 4 + wid;   // 16 segments of 1KB (8 rows)
            const int r = seg * 8 + srow;
            gld_lds16(Ab + (long)r * lda2 + kb + scol, smA + seg * 1024);
            gld_lds16(Bb + (long)r * ldb2 + kb + scol, smB + seg * 1024);
        }
        __syncthreads();                   // vmcnt(0) drain + barrier
#pragma unroll
        for (int kk = 0; kk < 2; ++kk) {
            bf16x8 af[4], bfm[4];
#pragma unroll
            for (int m = 0; m < 4; ++m)
                af[m] = *(const bf16x8*)(smA + (wr * 64 + m * 16 + (lane & 15)) * 128 + kk * 64 + (lane >> 4) * 16);
#pragma unroll
            for (int n = 0; n < 4; ++n)
                bfm[n] = *(const bf16x8*)(smB + (wc * 64 + n * 16 + (lane & 15)) * 128 + kk * 64 + (lane >> 4) * 16);
#pragma unroll
            for (int m = 0; m < 4; ++m)
#pragma unroll
                for (int n = 0; n < 4; ++n)
                    acc[m][n] = __builtin_amdgcn_mfma_f32_16x16x32_bf16(af[m], bfm[n], acc[m][n], 0, 0, 0);
        }
    }
    // epilogue: C/D layout col=lane&15, row=(lane>>4)*4+j
    const long row0 = (long)by * 128 + wr * 64 + (lane >> 4) * 4;
    const long col0 = (long)bx * 128 + wc * 64 + (lane & 15);
#pragma unroll
    for (int m = 0; m < 4; ++m)
#pragma unroll
        for (int n = 0; n < 4; ++n)
#pragma unroll
            for (int j = 0; j < 4; ++j) {
                const long r = row0 + m * 16 + j;
                const long c = col0 + n * 16;
                const float v = acc[m][n][j];
                if (MODE == 0) {
                    ((float*)C)[zb * sCb + r * ldc + c] = v;
                } else if (MODE == 1) {
                    ((float*)C)[zb * sCb + r * ldc + c] = v + add[zb * sAddb + r * ldadd + c];
                } else if (MODE == 2) {
                    float t = v + bias[c];
                    float gl = 0.5f * t * (1.0f + erff(t * 0.70710678118654752f));
                    ((unsigned short*)C)[zb * sCb + r * ldc + c] = f2bf(gl);
                } else {
                    ((float*)C)[zb * sCb + r * ldc + c] = v + bias[c] + add[zb * sAddb + r * ldadd + c];
                }
            }
}

// ---------- LayerNorm: f32 in -> bf16 out (+ optional sum(y^2), + zero pad) ----------
__global__ __launch_bounds__(256) void ln_kernel(
    const float* __restrict__ x, const float* __restrict__ gamma, const float* __restrict__ beta,
    unsigned short* __restrict__ out, int ldout, float* qout, int pad)
{
    const int tid = threadIdx.x;
    const long row = blockIdx.x;
    float4 v = ((const float4*)(x + row * 1024))[tid];
    float s = v.x + v.y + v.z + v.w;
    float s2 = v.x * v.x + v.y * v.y + v.z * v.z + v.w * v.w;
#pragma unroll
    for (int off = 32; off; off >>= 1) {
        s  += __shfl_down(s, off);
        s2 += __shfl_down(s2, off);
    }
    __shared__ float red[12];
    const int lane = tid & 63, wid = tid >> 6;
    if (lane == 0) { red[wid] = s; red[4 + wid] = s2; }
    __syncthreads();
    s  = red[0] + red[1] + red[2] + red[3];
    s2 = red[4] + red[5] + red[6] + red[7];
    const float mu = s * (1.0f / 1024.0f);
    const float var = s2 * (1.0f / 1024.0f) - mu * mu;
    const float rs = rsqrtf(var + 1e-5f);
    const float4 g = ((const float4*)gamma)[tid];
    const float4 b = ((const float4*)beta)[tid];
    unsigned short o0 = f2bf((v.x - mu) * rs * g.x + b.x);
    unsigned short o1 = f2bf((v.y - mu) * rs * g.y + b.y);
    unsigned short o2 = f2bf((v.z - mu) * rs * g.z + b.z);
    unsigned short o3 = f2bf((v.w - mu) * rs * g.w + b.w);
    ushort4 ov; ov.x = o0; ov.y = o1; ov.z = o2; ov.w = o3;
    ((ushort4*)(out + row * (long)ldout))[tid] = ov;
    if (pad && tid < 32) out[row * (long)ldout + 1056 + tid] = 0;  // zero K-pad
    if (qout) {  // q partial = sum over d of (rounded hn)^2
        float y0 = bf2f(o0), y1 = bf2f(o1), y2 = bf2f(o2), y3 = bf2f(o3);
        float sq = y0 * y0 + y1 * y1 + y2 * y2 + y3 * y3;
#pragma unroll
        for (int off = 32; off; off >>= 1) sq += __shfl_down(sq, off);
        if (lane == 0) red[8 + wid] = sq;
        __syncthreads();
        if (tid == 0) qout[row] = red[8] + red[9] + red[10] + red[11];
    }
}

// ---------- u = hn @ L (r=32), write bf16 into z cols [1024,1056), q += |u|^2 ----------
__global__ __launch_bounds__(256) void u_kernel(
    unsigned short* __restrict__ z, const float* __restrict__ L, float* __restrict__ q)
{
    const int tid = threadIdx.x;
    const long row = blockIdx.x;
    __shared__ float hn[1024];
    __shared__ float part[8][32];
    ushort4 uv = ((const ushort4*)(z + row * 1088))[tid];
    hn[tid * 4 + 0] = bf2f(uv.x);
    hn[tid * 4 + 1] = bf2f(uv.y);
    hn[tid * 4 + 2] = bf2f(uv.z);
    hn[tid * 4 + 3] = bf2f(uv.w);
    __syncthreads();
    const int j = tid & 31, grp = tid >> 5;
    float acc = 0.f;
    const float* Lp = L + j;
#pragma unroll 4
    for (int d = grp * 128; d < grp * 128 + 128; ++d)
        acc += hn[d] * Lp[(long)d * 32];
    part[grp][j] = acc;
    __syncthreads();
    if (tid < 32) {
        float u = 0.f;
#pragma unroll
        for (int g2 = 0; g2 < 8; ++g2) u += part[g2][tid];
        unsigned short ub = f2bf(u);
        z[row * 1088 + 1024 + tid] = ub;
        float uf = bf2f(ub);
        part[0][tid] = uf * uf;
    }
    __syncthreads();
    if (tid == 0) {
        float sq = 0.f;
#pragma unroll
        for (int t2 = 0; t2 < 32; ++t2) sq += part[0][t2];
        q[row] += sq;
    }
}

// ---------- softmax over row: logits = 2*S - q_j; write P bf16 in place ----------
__global__ __launch_bounds__(256) void softmax_kernel(
    float* S, const float* qb)
{
    const int tid = threadIdx.x;
    const long i = blockIdx.x, bl = blockIdx.y;
    float* Sr = S + (bl * 2048 + i) * 2048;
    const float* qr = qb + bl * 2048;
    float l[8];
    float mx = -1e30f;
#pragma unroll
    for (int c2 = 0; c2 < 8; ++c2) {
        const int jj = tid + c2 * 256;
        l[c2] = 2.0f * Sr[jj] - qr[jj];
        mx = fmaxf(mx, l[c2]);
    }
#pragma unroll
    for (int off = 32; off; off >>= 1) mx = fmaxf(mx, __shfl_xor(mx, off));
    __shared__ float red[8];
    const int lane = tid & 63, wid = tid >> 6;
    if (lane == 0) red[wid] = mx;
    __syncthreads();
    mx = fmaxf(fmaxf(red[0], red[1]), fmaxf(red[2], red[3]));
    float sum = 0.f;
#pragma unroll
    for (int c2 = 0; c2 < 8; ++c2) { l[c2] = __expf(l[c2] - mx); sum += l[c2]; }
#pragma unroll
    for (int off = 32; off; off >>= 1) sum += __shfl_xor(sum, off);
    if (lane == 0) red[4 + wid] = sum;
    __syncthreads();
    sum = red[4] + red[5] + red[6] + red[7];
    const float inv = 1.0f / sum;
    unsigned short* Pr = (unsigned short*)S + (bl * 2048 + i) * 4096;  // row stride 8192B
#pragma unroll
    for (int c2 = 0; c2 < 8; ++c2)
        Pr[tid + c2 * 256] = f2bf(l[c2] * inv);
}

// ---------- Vt[b][n][k] = z[b][k][n] (hn part only), bf16 ----------
__global__ __launch_bounds__(256) void transpose_v_kernel(
    const unsigned short* __restrict__ z, unsigned short* __restrict__ Vt, long sVtb)
{
    __shared__ unsigned short t[32][33];
    const int tid = threadIdx.x;
    const int tx = tid & 31, ty = tid >> 5;
    const long b = blockIdx.z;
    const long k0 = (long)blockIdx.x * 32, n0 = (long)blockIdx.y * 32;
#pragma unroll
    for (int r = 0; r < 32; r += 8)
        t[r + ty][tx] = z[(b * 2048 + k0 + r + ty) * 1088 + n0 + tx];
    __syncthreads();
#pragma unroll
    for (int r = 0; r < 32; r += 8)
        Vt[b * sVtb + (n0 + r + ty) * 2048 + k0 + tx] = t[tx][r + ty];
}

// ---------- Wt[c][r] = bf16(W[r][c]) ----------
__global__ __launch_bounds__(256) void cast_transpose_kernel(
    const float* __restrict__ W, unsigned short* __restrict__ Wt, int rows, int cols)
{
    __shared__ float t[32][33];
    const int tid = threadIdx.x;
    const int tx = tid & 31, ty = tid >> 5;
    const long r0 = (long)blockIdx.y * 32, c0 = (long)blockIdx.x * 32;
#pragma unroll
    for (int r = 0; r < 32; r += 8)
        t[r + ty][tx] = W[(r0 + r + ty) * (long)cols + c0 + tx];
    __syncthreads();
#pragma unroll
    for (int r = 0; r < 32; r += 8)
        Wt[(c0 + r + ty) * (long)rows + r0 + tx] = f2bf(t[tx][r + ty]);
}

// ---------- host ----------
// Workspace plan (ws_size >= 89.2 MB is measured-safe from R0's passing run):
//   q    : 32 KB                              (whole call)
//   pool : attention overlay  Vt 16.8 | Smat 67.1              (= 83.9 MB)
//          MLP overlay        W1t 8.4 | W2t 8.4 | hm 16.8 | hid 67.1/c
//   z (17.8 MB) lives in d_out (33.5 MB) — dead before PV overwrites it.
extern "C" void kernel_launch(void* const* d_in, const int* in_sizes, int n_in,
                              void* d_out, int out_size, void* d_ws, size_t ws_size,
                              hipStream_t stream)
{
    const float* x   = (const float*)d_in[0];
    const float* L   = (const float*)d_in[1];
    const float* W1  = (const float*)d_in[2];
    const float* b1  = (const float*)d_in[3];
    const float* W2  = (const float*)d_in[4];
    const float* b2  = (const float*)d_in[5];
    const float* g1  = (const float*)d_in[6];
    const float* be1 = (const float*)d_in[7];
    const float* g2  = (const float*)d_in[8];
    const float* be2 = (const float*)d_in[9];
    float* out = (float*)d_out;
    unsigned short* z = (unsigned short*)d_out;     // 8192 x 1088 bf16 in d_out

    char* wsp = (char*)d_ws;
    float* q = (float*)wsp;                          // 32 KB
    char* pool = wsp + 32768;
    // attention overlay
    unsigned short* Vt   = (unsigned short*)pool;                      // 4 x 1024 x 2048 bf16
    float*          Smat = (float*)(pool + 16777216);                  // 4 x 2048 x 2048 f32
    // MLP overlay (valid after PV has consumed Vt/Smat)
    unsigned short* W1t = (unsigned short*)pool;                       // 4096 x 1024 bf16
    unsigned short* W2t = (unsigned short*)(pool + 8388608);           // 1024 x 4096 bf16
    unsigned short* hm  = (unsigned short*)(pool + 16777216);          // 8192 x 1024 bf16
    unsigned short* hid = (unsigned short*)(pool + 33554432);          // 8192 x 4096 bf16 (or /2)
    const bool fullMLP = ws_size >= (size_t)32768 + 100663296 + 65536;

    // LN1 -> z[:,0:1024], q = |hn|^2, zero pad cols 1056:1088
    ln_kernel<<<8192, 256, 0, stream>>>(x, g1, be1, z, 1088, q, 1);
    // u = hn@L -> z[:,1024:1056], q += |u|^2
    u_kernel<<<8192, 256, 0, stream>>>(z, L, q);

    // ---- attention, all 4 batches in parallel ----
    transpose_v_kernel<<<dim3(64, 32, 4), 256, 0, stream>>>(z, Vt, (long)1024 * 2048);
    gemm_nt<0><<<dim3(16, 16, 4), 256, 0, stream>>>(
        z, 1088, (long)2048 * 1088,
        z, 1088, (long)2048 * 1088,
        Smat, 2048, (long)2048 * 2048,
        nullptr, 0, 0, nullptr, 1088);
    softmax_kernel<<<dim3(2048, 4), 256, 0, stream>>>(Smat, q);
    gemm_nt<1><<<dim3(8, 16, 4), 256, 0, stream>>>(
        (const unsigned short*)Smat, 4096, (long)2048 * 4096,
        Vt, 2048, (long)1024 * 2048,
        out, 1024, (long)2048 * 1024,
        x, 1024, (long)2048 * 1024,
        nullptr, 2048);

    // ---- MLP ----
    cast_transpose_kernel<<<dim3(128, 32), 256, 0, stream>>>(W1, W1t, 1024, 4096);
    cast_transpose_kernel<<<dim3(32, 128), 256, 0, stream>>>(W2, W2t, 4096, 1024);
    ln_kernel<<<8192, 256, 0, stream>>>(out, g2, be2, hm, 1024, nullptr, 0);
    if (fullMLP) {
        gemm_nt<2><<<dim3(32, 64, 1), 256, 0, stream>>>(
            hm, 1024, 0, W1t, 1024, 0,
            hid, 4096, 0, nullptr, 0, 0, b1, 1024);
        gemm_nt<3><<<dim3(8, 64, 1), 256, 0, stream>>>(
            hid, 4096, 0, W2t, 4096, 0,
            out, 1024, 0, out, 1024, 0, b2, 4096);
    } else {
        for (int c = 0; c < 2; ++c) {
            const unsigned short* hmc = hm + (size_t)c * 4096 * 1024;
            float* oc = out + (size_t)c * 4096 * 1024;
            gemm_nt<2><<<dim3(32, 32, 1), 256, 0, stream>>>(
                hmc, 1024, 0, W1t, 1024, 0,
                hid, 4096, 0, nullptr, 0, 0, b1, 1024);
            gemm_nt<3><<<dim3(8, 32, 1), 256, 0, stream>>>(
                hid, 4096, 0, W2t, 4096, 0,
                oc, 1024, 0, oc, 1024, 0, b2, 4096);
        }
    }
}

// Round 3
// 392.844 us; speedup vs baseline: 1.7844x; 1.0820x over previous
//
#include <hip/hip_runtime.h>
#include <cstdint>

// ---------- types ----------
typedef float f32x4 __attribute__((ext_vector_type(4)));
typedef __bf16 bf16x8 __attribute__((ext_vector_type(8)));

#define AS1 __attribute__((address_space(1)))
#define AS3 __attribute__((address_space(3)))

__device__ __forceinline__ void gld_lds16(const void* g, void* l) {
    // async global->LDS, 16B per lane; LDS dest = wave-uniform base + lane*16
    __builtin_amdgcn_global_load_lds((const AS1 void*)g, (AS3 void*)l, 16, 0, 0);
}

__device__ __forceinline__ unsigned short f2bf(float f) {  // RNE f32->bf16
    unsigned u = __builtin_bit_cast(unsigned, f);
    u = u + 0x7fffu + ((u >> 16) & 1u);
    return (unsigned short)(u >> 16);
}
__device__ __forceinline__ float bf2f(unsigned short h) {
    unsigned u = ((unsigned)h) << 16;
    return __builtin_bit_cast(float, u);
}

__device__ __forceinline__ void bar() {
    asm volatile("" ::: "memory");
    __builtin_amdgcn_s_barrier();
    asm volatile("" ::: "memory");
}

// ---------- deep-pipelined GEMM: C = A @ B^T, A[M][K], B[N][K], bf16, f32 accum
// 256xBN tile, BK=32, 8 waves (2M x 4N), per-wave 128 x BN/4 output.
// 4 LDS buffers, prefetch depth 3, counted vmcnt (never 0 in main loop).
// MODE 0: C f32 = acc                  (S matrix)
// MODE 1: C f32 = acc + add            (PV + residual -> x1)
// MODE 2: C bf16 = gelu(acc + bias)    (MLP hidden)
// MODE 3: C f32 = acc + bias + add     (MLP out + residual)
template<int BN, int MODE>
__global__ __launch_bounds__(512, 2) void gemm_nt2(
    const unsigned short* __restrict__ A, long lda, long sAb,
    const unsigned short* __restrict__ B, long ldb, long sBb,
    void* C, long ldc, long sCb,
    const float* add, long ldadd, long sAddb,
    const float* __restrict__ bias, int K)
{
    constexpr int NR  = BN / 64;            // N-frags per wave
    constexpr int BUF = 16384 + BN * 64;    // bytes/buffer: A 256x32x2 + B BNx32x2
    __shared__ char sm[4 * BUF];
    const int tid = threadIdx.x, lane = tid & 63, wid = tid >> 6;
    const int wr = wid >> 2, wc = wid & 3;  // 2M x 4N wave grid

    const long zb = blockIdx.z;
    // T1: bijective XCD-aware swizzle (m204)
    const int nwg  = gridDim.x * gridDim.y;
    const int orig = blockIdx.y * gridDim.x + blockIdx.x;
    const int q8 = nwg >> 3, r8 = nwg & 7;
    const int xcd = orig & 7;
    const int wg  = (xcd < r8 ? xcd * (q8 + 1) : r8 * (q8 + 1) + (xcd - r8) * q8) + (orig >> 3);
    const int bx = wg % gridDim.x, by = wg / gridDim.x;

    const char* Ab = (const char*)(A + zb * sAb + (long)by * 256 * lda);
    const char* Bb = (const char*)(B + zb * sBb + (long)bx * BN * ldb);
    const long ldaB = lda * 2, ldbB = ldb * 2;
    const int  grow = tid >> 2;             // 0..127: row within 128-row chunk
    const long gcol = (long)(tid & 3) * 16; // 16B chunk within 64B row

    // stage K-tile kt into buffer bi. LDS linear: row*64 + chunk*16 == tid*16.
    auto stage = [&](int kt, int bi) {
        const char* As = Ab + (long)kt * 64 + gcol;
        const char* Bs = Bb + (long)kt * 64 + gcol;
        char* d = sm + bi * BUF + wid * 1024;   // wave-uniform base; HW adds lane*16
#pragma unroll
        for (int i = 0; i < 2; ++i)
            gld_lds16(As + (long)(i * 128 + grow) * ldaB, d + i * 8192);
#pragma unroll
        for (int i = 0; i < BN / 128; ++i)
            gld_lds16(Bs + (long)(i * 128 + grow) * ldbB, d + 16384 + i * 8192);
    };

    f32x4 acc[8][NR] = {};
    const int NT = K / 32;
    stage(0, 0);
    if (NT > 1) stage(1, 1);
    if (NT > 2) stage(2, 2);

    for (int t = 0; t < NT; ++t) {
        const int rem = NT - t;
        if (rem > 3) {
            stage(t + 3, (t + 3) & 3);
            // outstanding after wait = 3 tiles ahead (tile t fully landed)
            if constexpr (BN == 256) asm volatile("s_waitcnt vmcnt(12)" ::: "memory");
            else                     asm volatile("s_waitcnt vmcnt(9)"  ::: "memory");
        } else if (rem == 3) {
            if constexpr (BN == 256) asm volatile("s_waitcnt vmcnt(8)" ::: "memory");
            else                     asm volatile("s_waitcnt vmcnt(6)" ::: "memory");
        } else if (rem == 2) {
            if constexpr (BN == 256) asm volatile("s_waitcnt vmcnt(4)" ::: "memory");
            else                     asm volatile("s_waitcnt vmcnt(3)" ::: "memory");
        } else {
            asm volatile("s_waitcnt vmcnt(0)" ::: "memory");
        }
        bar();                               // everyone's tile-t data landed

        const char* bufA = sm + (t & 3) * BUF;
        const char* bufB = bufA + 16384;
        bf16x8 af[8], bfr[NR];
#pragma unroll
        for (int m = 0; m < 8; ++m)
            af[m] = *(const bf16x8*)(bufA + (wr * 128 + m * 16 + (lane & 15)) * 64 + (lane >> 4) * 16);
#pragma unroll
        for (int n = 0; n < NR; ++n)
            bfr[n] = *(const bf16x8*)(bufB + (wc * 16 * NR + n * 16 + (lane & 15)) * 64 + (lane >> 4) * 16);
        __builtin_amdgcn_s_setprio(1);
#pragma unroll
        for (int m = 0; m < 8; ++m)
#pragma unroll
            for (int n = 0; n < NR; ++n)
                acc[m][n] = __builtin_amdgcn_mfma_f32_16x16x32_bf16(af[m], bfr[n], acc[m][n], 0, 0, 0);
        __builtin_amdgcn_s_setprio(0);
        asm volatile("s_waitcnt lgkmcnt(0)" ::: "memory");  // my ds_reads done
        __builtin_amdgcn_sched_barrier(0);
        bar();                               // now next stage may overwrite buf[t&3] (t+4)
    }

    // epilogue: C/D layout col=lane&15, row=(lane>>4)*4+j
    const long row0 = (long)by * 256 + wr * 128 + (lane >> 4) * 4;
    const long col0 = (long)bx * BN + wc * 16 * NR + (lane & 15);
#pragma unroll
    for (int m = 0; m < 8; ++m)
#pragma unroll
        for (int n = 0; n < NR; ++n)
#pragma unroll
            for (int j = 0; j < 4; ++j) {
                const long r = row0 + m * 16 + j;
                const long c = col0 + n * 16;
                const float v = acc[m][n][j];
                if (MODE == 0) {
                    ((float*)C)[zb * sCb + r * ldc + c] = v;
                } else if (MODE == 1) {
                    ((float*)C)[zb * sCb + r * ldc + c] = v + add[zb * sAddb + r * ldadd + c];
                } else if (MODE == 2) {
                    float tt = v + bias[c];
                    float gl = 0.5f * tt * (1.0f + erff(tt * 0.70710678118654752f));
                    ((unsigned short*)C)[zb * sCb + r * ldc + c] = f2bf(gl);
                } else {
                    ((float*)C)[zb * sCb + r * ldc + c] = v + bias[c] + add[zb * sAddb + r * ldadd + c];
                }
            }
}

// ---------- LayerNorm: f32 in -> bf16 out (+ optional sum(y^2), + zero pad) ----------
__global__ __launch_bounds__(256) void ln_kernel(
    const float* __restrict__ x, const float* __restrict__ gamma, const float* __restrict__ beta,
    unsigned short* __restrict__ out, int ldout, float* qout, int pad)
{
    const int tid = threadIdx.x;
    const long row = blockIdx.x;
    float4 v = ((const float4*)(x + row * 1024))[tid];
    float s = v.x + v.y + v.z + v.w;
    float s2 = v.x * v.x + v.y * v.y + v.z * v.z + v.w * v.w;
#pragma unroll
    for (int off = 32; off; off >>= 1) {
        s  += __shfl_down(s, off);
        s2 += __shfl_down(s2, off);
    }
    __shared__ float red[12];
    const int lane = tid & 63, wid = tid >> 6;
    if (lane == 0) { red[wid] = s; red[4 + wid] = s2; }
    __syncthreads();
    s  = red[0] + red[1] + red[2] + red[3];
    s2 = red[4] + red[5] + red[6] + red[7];
    const float mu = s * (1.0f / 1024.0f);
    const float var = s2 * (1.0f / 1024.0f) - mu * mu;
    const float rs = rsqrtf(var + 1e-5f);
    const float4 g = ((const float4*)gamma)[tid];
    const float4 b = ((const float4*)beta)[tid];
    unsigned short o0 = f2bf((v.x - mu) * rs * g.x + b.x);
    unsigned short o1 = f2bf((v.y - mu) * rs * g.y + b.y);
    unsigned short o2 = f2bf((v.z - mu) * rs * g.z + b.z);
    unsigned short o3 = f2bf((v.w - mu) * rs * g.w + b.w);
    ushort4 ov; ov.x = o0; ov.y = o1; ov.z = o2; ov.w = o3;
    ((ushort4*)(out + row * (long)ldout))[tid] = ov;
    if (pad && tid < 32) out[row * (long)ldout + 1056 + tid] = 0;  // zero K-pad
    if (qout) {  // q partial = sum over d of (rounded hn)^2
        float y0 = bf2f(o0), y1 = bf2f(o1), y2 = bf2f(o2), y3 = bf2f(o3);
        float sq = y0 * y0 + y1 * y1 + y2 * y2 + y3 * y3;
#pragma unroll
        for (int off = 32; off; off >>= 1) sq += __shfl_down(sq, off);
        if (lane == 0) red[8 + wid] = sq;
        __syncthreads();
        if (tid == 0) qout[row] = red[8] + red[9] + red[10] + red[11];
    }
}

// ---------- u = hn @ L (r=32), write bf16 into z cols [1024,1056), q += |u|^2 ----------
__global__ __launch_bounds__(256) void u_kernel(
    unsigned short* __restrict__ z, const float* __restrict__ L, float* __restrict__ q)
{
    const int tid = threadIdx.x;
    const long row = blockIdx.x;
    __shared__ float hn[1024];
    __shared__ float part[8][32];
    ushort4 uv = ((const ushort4*)(z + row * 1088))[tid];
    hn[tid * 4 + 0] = bf2f(uv.x);
    hn[tid * 4 + 1] = bf2f(uv.y);
    hn[tid * 4 + 2] = bf2f(uv.z);
    hn[tid * 4 + 3] = bf2f(uv.w);
    __syncthreads();
    const int j = tid & 31, grp = tid >> 5;
    float acc = 0.f;
    const float* Lp = L + j;
#pragma unroll 4
    for (int d = grp * 128; d < grp * 128 + 128; ++d)
        acc += hn[d] * Lp[(long)d * 32];
    part[grp][j] = acc;
    __syncthreads();
    if (tid < 32) {
        float u = 0.f;
#pragma unroll
        for (int g2 = 0; g2 < 8; ++g2) u += part[g2][tid];
        unsigned short ub = f2bf(u);
        z[row * 1088 + 1024 + tid] = ub;
        float uf = bf2f(ub);
        part[0][tid] = uf * uf;
    }
    __syncthreads();
    if (tid == 0) {
        float sq = 0.f;
#pragma unroll
        for (int t2 = 0; t2 < 32; ++t2) sq += part[0][t2];
        q[row] += sq;
    }
}

// ---------- softmax over row: logits = 2*S - q_j; write P bf16 in place ----------
__global__ __launch_bounds__(256) void softmax_kernel(
    float* S, const float* qb)
{
    const int tid = threadIdx.x;
    const long i = blockIdx.x, bl = blockIdx.y;
    float* Sr = S + (bl * 2048 + i) * 2048;
    const float* qr = qb + bl * 2048;
    float l[8];
    float mx = -1e30f;
#pragma unroll
    for (int c2 = 0; c2 < 8; ++c2) {
        const int jj = tid + c2 * 256;
        l[c2] = 2.0f * Sr[jj] - qr[jj];
        mx = fmaxf(mx, l[c2]);
    }
#pragma unroll
    for (int off = 32; off; off >>= 1) mx = fmaxf(mx, __shfl_xor(mx, off));
    __shared__ float red[8];
    const int lane = tid & 63, wid = tid >> 6;
    if (lane == 0) red[wid] = mx;
    __syncthreads();
    mx = fmaxf(fmaxf(red[0], red[1]), fmaxf(red[2], red[3]));
    float sum = 0.f;
#pragma unroll
    for (int c2 = 0; c2 < 8; ++c2) { l[c2] = __expf(l[c2] - mx); sum += l[c2]; }
#pragma unroll
    for (int off = 32; off; off >>= 1) sum += __shfl_xor(sum, off);
    if (lane == 0) red[4 + wid] = sum;
    __syncthreads();
    sum = red[4] + red[5] + red[6] + red[7];
    const float inv = 1.0f / sum;
    unsigned short* Pr = (unsigned short*)S + (bl * 2048 + i) * 4096;  // row stride 8192B
#pragma unroll
    for (int c2 = 0; c2 < 8; ++c2)
        Pr[tid + c2 * 256] = f2bf(l[c2] * inv);
}

// ---------- Vt[b][n][k] = z[b][k][n] (hn part only), bf16 ----------
__global__ __launch_bounds__(256) void transpose_v_kernel(
    const unsigned short* __restrict__ z, unsigned short* __restrict__ Vt, long sVtb)
{
    __shared__ unsigned short t[32][33];
    const int tid = threadIdx.x;
    const int tx = tid & 31, ty = tid >> 5;
    const long b = blockIdx.z;
    const long k0 = (long)blockIdx.x * 32, n0 = (long)blockIdx.y * 32;
#pragma unroll
    for (int r = 0; r < 32; r += 8)
        t[r + ty][tx] = z[(b * 2048 + k0 + r + ty) * 1088 + n0 + tx];
    __syncthreads();
#pragma unroll
    for (int r = 0; r < 32; r += 8)
        Vt[b * sVtb + (n0 + r + ty) * 2048 + k0 + tx] = t[tx][r + ty];
}

// ---------- Wt[c][r] = bf16(W[r][c]) ----------
__global__ __launch_bounds__(256) void cast_transpose_kernel(
    const float* __restrict__ W, unsigned short* __restrict__ Wt, int rows, int cols)
{
    __shared__ float t[32][33];
    const int tid = threadIdx.x;
    const int tx = tid & 31, ty = tid >> 5;
    const long r0 = (long)blockIdx.y * 32, c0 = (long)blockIdx.x * 32;
#pragma unroll
    for (int r = 0; r < 32; r += 8)
        t[r + ty][tx] = W[(r0 + r + ty) * (long)cols + c0 + tx];
    __syncthreads();
#pragma unroll
    for (int r = 0; r < 32; r += 8)
        Wt[(c0 + r + ty) * (long)rows + r0 + tx] = f2bf(t[tx][r + ty]);
}

// ---------- host ----------
// Workspace plan (>= 89.2 MB measured-safe):
//   q    : 32 KB
//   pool : attention overlay  Vt 16.8 | Smat 67.1             (= 83.9 MB)
//          MLP overlay        W1t 8.4 | W2t 8.4 | hm 16.8 | hid 67.1/c
//   z (17.8 MB) lives in d_out (33.5 MB) — dead before PV overwrites it.
extern "C" void kernel_launch(void* const* d_in, const int* in_sizes, int n_in,
                              void* d_out, int out_size, void* d_ws, size_t ws_size,
                              hipStream_t stream)
{
    const float* x   = (const float*)d_in[0];
    const float* L   = (const float*)d_in[1];
    const float* W1  = (const float*)d_in[2];
    const float* b1  = (const float*)d_in[3];
    const float* W2  = (const float*)d_in[4];
    const float* b2  = (const float*)d_in[5];
    const float* g1  = (const float*)d_in[6];
    const float* be1 = (const float*)d_in[7];
    const float* g2  = (const float*)d_in[8];
    const float* be2 = (const float*)d_in[9];
    float* out = (float*)d_out;
    unsigned short* z = (unsigned short*)d_out;     // 8192 x 1088 bf16 in d_out

    char* wsp = (char*)d_ws;
    float* q = (float*)wsp;                          // 32 KB
    char* pool = wsp + 32768;
    // attention overlay
    unsigned short* Vt   = (unsigned short*)pool;                      // 4 x 1024 x 2048 bf16
    float*          Smat = (float*)(pool + 16777216);                  // 4 x 2048 x 2048 f32
    // MLP overlay (valid after PV has consumed Vt/Smat)
    unsigned short* W1t = (unsigned short*)pool;                       // 4096 x 1024 bf16
    unsigned short* W2t = (unsigned short*)(pool + 8388608);           // 1024 x 4096 bf16
    unsigned short* hm  = (unsigned short*)(pool + 16777216);          // 8192 x 1024 bf16
    unsigned short* hid = (unsigned short*)(pool + 33554432);          // 8192 x 4096 bf16 (or /2)
    const bool fullMLP = ws_size >= (size_t)32768 + 100663296 + 65536;

    // LN1 -> z[:,0:1024], q = |hn|^2, zero pad cols 1056:1088
    ln_kernel<<<8192, 256, 0, stream>>>(x, g1, be1, z, 1088, q, 1);
    // u = hn@L -> z[:,1024:1056], q += |u|^2
    u_kernel<<<8192, 256, 0, stream>>>(z, L, q);

    // ---- attention, all 4 batches in parallel ----
    transpose_v_kernel<<<dim3(64, 32, 4), 256, 0, stream>>>(z, Vt, (long)1024 * 2048);
    gemm_nt2<256, 0><<<dim3(8, 8, 4), 512, 0, stream>>>(
        z, 1088, (long)2048 * 1088,
        z, 1088, (long)2048 * 1088,
        Smat, 2048, (long)2048 * 2048,
        nullptr, 0, 0, nullptr, 1088);
    softmax_kernel<<<dim3(2048, 4), 256, 0, stream>>>(Smat, q);
    gemm_nt2<128, 1><<<dim3(8, 8, 4), 512, 0, stream>>>(
        (const unsigned short*)Smat, 4096, (long)2048 * 4096,
        Vt, 2048, (long)1024 * 2048,
        out, 1024, (long)2048 * 1024,
        x, 1024, (long)2048 * 1024,
        nullptr, 2048);

    // ---- MLP ----
    cast_transpose_kernel<<<dim3(128, 32), 256, 0, stream>>>(W1, W1t, 1024, 4096);
    cast_transpose_kernel<<<dim3(32, 128), 256, 0, stream>>>(W2, W2t, 4096, 1024);
    ln_kernel<<<8192, 256, 0, stream>>>(out, g2, be2, hm, 1024, nullptr, 0);
    if (fullMLP) {
        gemm_nt2<256, 2><<<dim3(16, 32, 1), 512, 0, stream>>>(
            hm, 1024, 0, W1t, 1024, 0,
            hid, 4096, 0, nullptr, 0, 0, b1, 1024);
        gemm_nt2<128, 3><<<dim3(8, 32, 1), 512, 0, stream>>>(
            hid, 4096, 0, W2t, 4096, 0,
            out, 1024, 0, out, 1024, 0, b2, 4096);
    } else {
        for (int c = 0; c < 2; ++c) {
            const unsigned short* hmc = hm + (size_t)c * 4096 * 1024;
            float* oc = out + (size_t)c * 4096 * 1024;
            gemm_nt2<256, 2><<<dim3(16, 16, 1), 512, 0, stream>>>(
                hmc, 1024, 0, W1t, 1024, 0,
                hid, 4096, 0, nullptr, 0, 0, b1, 1024);
            gemm_nt2<128, 3><<<dim3(8, 16, 1), 512, 0, stream>>>(
                hid, 4096, 0, W2t, 4096, 0,
                oc, 1024, 0, oc, 1024, 0, b2, 4096);
        }
    }
}

// Round 4
// 381.745 us; speedup vs baseline: 1.8363x; 1.0291x over previous
//
#include <hip/hip_runtime.h>
#include <cstdint>

// ---------- types ----------
typedef float f32x4 __attribute__((ext_vector_type(4)));
typedef __bf16 bf16x8 __attribute__((ext_vector_type(8)));

#define AS1 __attribute__((address_space(1)))
#define AS3 __attribute__((address_space(3)))

__device__ __forceinline__ void gld_lds16(const void* g, void* l) {
    // async global->LDS, 16B per lane; LDS dest = wave-uniform base + lane*16
    __builtin_amdgcn_global_load_lds((const AS1 void*)g, (AS3 void*)l, 16, 0, 0);
}

__device__ __forceinline__ unsigned short f2bf(float f) {  // RNE f32->bf16
    unsigned u = __builtin_bit_cast(unsigned, f);
    u = u + 0x7fffu + ((u >> 16) & 1u);
    return (unsigned short)(u >> 16);
}
__device__ __forceinline__ float bf2f(unsigned short h) {
    unsigned u = ((unsigned)h) << 16;
    return __builtin_bit_cast(float, u);
}

__device__ __forceinline__ void bar() {
    asm volatile("" ::: "memory");
    __builtin_amdgcn_s_barrier();
    asm volatile("" ::: "memory");
}

#define WAITVM(n) asm volatile("s_waitcnt vmcnt(" #n ")" ::: "memory")
#define LGKM0     asm volatile("s_waitcnt lgkmcnt(0)" ::: "memory")
#define SCHED0    __builtin_amdgcn_sched_barrier(0)

// ---------- deep-pipelined GEMM: C = A @ B^T, A[M][K], B[N][K], bf16, f32 accum
// 256xBN tile, BK=32 (64B LDS rows), 8 waves (2M x 4N), per-wave 128 x BN/4.
// 4 LDS buffers, DMA prefetch depth 3 (counted vmcnt, never 0 mid-loop),
// register-double-buffered fragments (ds_read of tile t+1 overlaps MFMA of t),
// XOR bank swizzle: chunk' = chunk ^ (row&3) ^ ((row>>2)&1)  (2-way max).
// MODE 0: C f32 = acc; 1: +add; 2: bf16 gelu(acc+bias); 3: f32 acc+bias+add
template<int BN, int MODE>
__global__ __launch_bounds__(512, 2) void gemm_nt3(
    const unsigned short* __restrict__ A, long lda, long sAb,
    const unsigned short* __restrict__ B, long ldb, long sBb,
    void* C, long ldc, long sCb,
    const float* add, long ldadd, long sAddb,
    const float* __restrict__ bias, int K)
{
    constexpr int NR  = BN / 64;            // N-frags per wave
    constexpr int BUF = 16384 + BN * 64;    // bytes/buffer: A 256x32x2 + B BNx32x2
    __shared__ char sm[4 * BUF];
    const int tid = threadIdx.x, lane = tid & 63, wid = tid >> 6;
    const int wr = wid >> 2, wc = wid & 3;  // 2M x 4N wave grid

    const long zb = blockIdx.z;
    // T1: bijective XCD-aware swizzle (m204)
    const int nwg  = gridDim.x * gridDim.y;
    const int orig = blockIdx.y * gridDim.x + blockIdx.x;
    const int q8 = nwg >> 3, r8 = nwg & 7;
    const int xcd = orig & 7;
    const int wg  = (xcd < r8 ? xcd * (q8 + 1) : r8 * (q8 + 1) + (xcd - r8) * q8) + (orig >> 3);
    const int bx = wg % gridDim.x, by = wg / gridDim.x;

    const char* Ab = (const char*)(A + zb * sAb + (long)by * 256 * lda);
    const char* Bb = (const char*)(B + zb * sBb + (long)bx * BN * ldb);
    const long ldaB = lda * 2, ldbB = ldb * 2;
    const int  grow = tid >> 2;             // 0..127: row within 128-row chunk
    // stage-side swizzled global chunk:  c = (lane&3) ^ (row&3) ^ ((row>>2)&1)
    const long gsw  = (long)((((lane & 3) ^ ((lane >> 2) & 3) ^ ((lane >> 4) & 1))) << 4);
    // read-side swizzled chunk offset:   k = (lane>>4) ^ (row&3) ^ ((row>>2)&1)
    const int  koff16 = (((lane >> 4) ^ (lane & 3) ^ ((lane >> 2) & 1)) << 4);

    // stage K-tile kt into buffer bi. LDS stays LINEAR (lane*16); global src swizzled.
    auto stage = [&](int kt, int bi) {
        const char* As = Ab + (long)kt * 64 + gsw;
        const char* Bs = Bb + (long)kt * 64 + gsw;
        char* d = sm + bi * BUF + wid * 1024;   // wave-uniform base; HW adds lane*16
#pragma unroll
        for (int i = 0; i < 2; ++i)
            gld_lds16(As + (long)(i * 128 + grow) * ldaB, d + i * 8192);
#pragma unroll
        for (int i = 0; i < BN / 128; ++i)
            gld_lds16(Bs + (long)(i * 128 + grow) * ldbB, d + 16384 + i * 8192);
    };

    auto rdfrags = [&](const char* bufA, bf16x8* af, bf16x8* bfr) {
        const char* bufB = bufA + 16384;
#pragma unroll
        for (int m = 0; m < 8; ++m)
            af[m] = *(const bf16x8*)(bufA + (wr * 128 + m * 16 + (lane & 15)) * 64 + koff16);
#pragma unroll
        for (int n = 0; n < NR; ++n)
            bfr[n] = *(const bf16x8*)(bufB + (wc * 16 * NR + n * 16 + (lane & 15)) * 64 + koff16);
    };

    f32x4 acc[8][NR] = {};
    auto domfma = [&](const bf16x8* af, const bf16x8* bfr) {
        __builtin_amdgcn_s_setprio(1);
#pragma unroll
        for (int m = 0; m < 8; ++m)
#pragma unroll
            for (int n = 0; n < NR; ++n)
                acc[m][n] = __builtin_amdgcn_mfma_f32_16x16x32_bf16(af[m], bfr[n], acc[m][n], 0, 0, 0);
        __builtin_amdgcn_s_setprio(0);
    };

    const int NT = K / 32;                  // even, >= 4 for all our shapes
    bf16x8 a0[8], b0[NR], a1[8], b1[NR];

    stage(0, 0); stage(1, 1); stage(2, 2);
    if constexpr (BN == 256) WAITVM(8); else WAITVM(6);   // tile0 landed (own)
    bar();                                                 // tile0 landed (all)
    rdfrags(sm, a0, b0);
    SCHED0;

#pragma unroll 1
    for (int t = 0; t < NT; t += 2) {
        // ---- even half: compute tile t, prefetch frags of t+1 ----
        if (t + 3 < NT) {
            stage(t + 3, (t + 3) & 3);
            if constexpr (BN == 256) WAITVM(8); else WAITVM(6);   // t+1 landed
        } else {
            WAITVM(0);
        }
        bar();
        rdfrags(sm + ((t + 1) & 3) * BUF, a1, b1);
        SCHED0;                    // reads issue before MFMA cluster
        domfma(a0, b0);
        LGKM0; SCHED0;             // a1/b1 valid; buf reads drained

        // ---- odd half: compute tile t+1, prefetch frags of t+2 ----
        if (t + 2 < NT) {
            if (t + 4 < NT) {
                stage(t + 4, (t + 4) & 3);
                if constexpr (BN == 256) WAITVM(8); else WAITVM(6);   // t+2 landed
            } else {
                if constexpr (BN == 256) WAITVM(4); else WAITVM(3);
            }
            bar();
            rdfrags(sm + ((t + 2) & 3) * BUF, a0, b0);
            SCHED0;
        }
        domfma(a1, b1);
        LGKM0; SCHED0;
    }

    // epilogue: C/D layout col=lane&15, row=(lane>>4)*4+j
    const long row0 = (long)by * 256 + wr * 128 + (lane >> 4) * 4;
    const long col0 = (long)bx * BN + wc * 16 * NR + (lane & 15);
#pragma unroll
    for (int m = 0; m < 8; ++m)
#pragma unroll
        for (int n = 0; n < NR; ++n)
#pragma unroll
            for (int j = 0; j < 4; ++j) {
                const long r = row0 + m * 16 + j;
                const long c = col0 + n * 16;
                const float v = acc[m][n][j];
                if (MODE == 0) {
                    ((float*)C)[zb * sCb + r * ldc + c] = v;
                } else if (MODE == 1) {
                    ((float*)C)[zb * sCb + r * ldc + c] = v + add[zb * sAddb + r * ldadd + c];
                } else if (MODE == 2) {
                    float tt = v + bias[c];
                    float gl = 0.5f * tt * (1.0f + erff(tt * 0.70710678118654752f));
                    ((unsigned short*)C)[zb * sCb + r * ldc + c] = f2bf(gl);
                } else {
                    ((float*)C)[zb * sCb + r * ldc + c] = v + bias[c] + add[zb * sAddb + r * ldadd + c];
                }
            }
}

// ---------- LayerNorm: f32 in -> bf16 out (+ optional sum(y^2), + zero pad) ----------
__global__ __launch_bounds__(256) void ln_kernel(
    const float* __restrict__ x, const float* __restrict__ gamma, const float* __restrict__ beta,
    unsigned short* __restrict__ out, int ldout, float* qout, int pad)
{
    const int tid = threadIdx.x;
    const long row = blockIdx.x;
    float4 v = ((const float4*)(x + row * 1024))[tid];
    float s = v.x + v.y + v.z + v.w;
    float s2 = v.x * v.x + v.y * v.y + v.z * v.z + v.w * v.w;
#pragma unroll
    for (int off = 32; off; off >>= 1) {
        s  += __shfl_down(s, off);
        s2 += __shfl_down(s2, off);
    }
    __shared__ float red[12];
    const int lane = tid & 63, wid = tid >> 6;
    if (lane == 0) { red[wid] = s; red[4 + wid] = s2; }
    __syncthreads();
    s  = red[0] + red[1] + red[2] + red[3];
    s2 = red[4] + red[5] + red[6] + red[7];
    const float mu = s * (1.0f / 1024.0f);
    const float var = s2 * (1.0f / 1024.0f) - mu * mu;
    const float rs = rsqrtf(var + 1e-5f);
    const float4 g = ((const float4*)gamma)[tid];
    const float4 b = ((const float4*)beta)[tid];
    unsigned short o0 = f2bf((v.x - mu) * rs * g.x + b.x);
    unsigned short o1 = f2bf((v.y - mu) * rs * g.y + b.y);
    unsigned short o2 = f2bf((v.z - mu) * rs * g.z + b.z);
    unsigned short o3 = f2bf((v.w - mu) * rs * g.w + b.w);
    ushort4 ov; ov.x = o0; ov.y = o1; ov.z = o2; ov.w = o3;
    ((ushort4*)(out + row * (long)ldout))[tid] = ov;
    if (pad && tid < 32) out[row * (long)ldout + 1056 + tid] = 0;  // zero K-pad
    if (qout) {  // q partial = sum over d of (rounded hn)^2
        float y0 = bf2f(o0), y1 = bf2f(o1), y2 = bf2f(o2), y3 = bf2f(o3);
        float sq = y0 * y0 + y1 * y1 + y2 * y2 + y3 * y3;
#pragma unroll
        for (int off = 32; off; off >>= 1) sq += __shfl_down(sq, off);
        if (lane == 0) red[8 + wid] = sq;
        __syncthreads();
        if (tid == 0) qout[row] = red[8] + red[9] + red[10] + red[11];
    }
}

// ---------- u = hn @ L (r=32), write bf16 into z cols [1024,1056), q += |u|^2 ----------
__global__ __launch_bounds__(256) void u_kernel(
    unsigned short* __restrict__ z, const float* __restrict__ L, float* __restrict__ q)
{
    const int tid = threadIdx.x;
    const long row = blockIdx.x;
    __shared__ float hn[1024];
    __shared__ float part[8][32];
    ushort4 uv = ((const ushort4*)(z + row * 1088))[tid];
    hn[tid * 4 + 0] = bf2f(uv.x);
    hn[tid * 4 + 1] = bf2f(uv.y);
    hn[tid * 4 + 2] = bf2f(uv.z);
    hn[tid * 4 + 3] = bf2f(uv.w);
    __syncthreads();
    const int j = tid & 31, grp = tid >> 5;
    float acc = 0.f;
    const float* Lp = L + j;
#pragma unroll 4
    for (int d = grp * 128; d < grp * 128 + 128; ++d)
        acc += hn[d] * Lp[(long)d * 32];
    part[grp][j] = acc;
    __syncthreads();
    if (tid < 32) {
        float u = 0.f;
#pragma unroll
        for (int g2 = 0; g2 < 8; ++g2) u += part[g2][tid];
        unsigned short ub = f2bf(u);
        z[row * 1088 + 1024 + tid] = ub;
        float uf = bf2f(ub);
        part[0][tid] = uf * uf;
    }
    __syncthreads();
    if (tid == 0) {
        float sq = 0.f;
#pragma unroll
        for (int t2 = 0; t2 < 32; ++t2) sq += part[0][t2];
        q[row] += sq;
    }
}

// ---------- softmax over row: logits = 2*S - q_j; write P bf16 in place ----------
__global__ __launch_bounds__(256) void softmax_kernel(
    float* S, const float* qb)
{
    const int tid = threadIdx.x;
    const long i = blockIdx.x, bl = blockIdx.y;
    float* Sr = S + (bl * 2048 + i) * 2048;
    const float* qr = qb + bl * 2048;
    float l[8];
    float mx = -1e30f;
#pragma unroll
    for (int c2 = 0; c2 < 8; ++c2) {
        const int jj = tid + c2 * 256;
        l[c2] = 2.0f * Sr[jj] - qr[jj];
        mx = fmaxf(mx, l[c2]);
    }
#pragma unroll
    for (int off = 32; off; off >>= 1) mx = fmaxf(mx, __shfl_xor(mx, off));
    __shared__ float red[8];
    const int lane = tid & 63, wid = tid >> 6;
    if (lane == 0) red[wid] = mx;
    __syncthreads();
    mx = fmaxf(fmaxf(red[0], red[1]), fmaxf(red[2], red[3]));
    float sum = 0.f;
#pragma unroll
    for (int c2 = 0; c2 < 8; ++c2) { l[c2] = __expf(l[c2] - mx); sum += l[c2]; }
#pragma unroll
    for (int off = 32; off; off >>= 1) sum += __shfl_xor(sum, off);
    if (lane == 0) red[4 + wid] = sum;
    __syncthreads();
    sum = red[4] + red[5] + red[6] + red[7];
    const float inv = 1.0f / sum;
    unsigned short* Pr = (unsigned short*)S + (bl * 2048 + i) * 4096;  // row stride 8192B
#pragma unroll
    for (int c2 = 0; c2 < 8; ++c2)
        Pr[tid + c2 * 256] = f2bf(l[c2] * inv);
}

// ---------- Vt[b][n][k] = z[b][k][n] (hn part only), bf16 ----------
__global__ __launch_bounds__(256) void transpose_v_kernel(
    const unsigned short* __restrict__ z, unsigned short* __restrict__ Vt, long sVtb)
{
    __shared__ unsigned short t[32][33];
    const int tid = threadIdx.x;
    const int tx = tid & 31, ty = tid >> 5;
    const long b = blockIdx.z;
    const long k0 = (long)blockIdx.x * 32, n0 = (long)blockIdx.y * 32;
#pragma unroll
    for (int r = 0; r < 32; r += 8)
        t[r + ty][tx] = z[(b * 2048 + k0 + r + ty) * 1088 + n0 + tx];
    __syncthreads();
#pragma unroll
    for (int r = 0; r < 32; r += 8)
        Vt[b * sVtb + (n0 + r + ty) * 2048 + k0 + tx] = t[tx][r + ty];
}

// ---------- Wt[c][r] = bf16(W[r][c]) ----------
__global__ __launch_bounds__(256) void cast_transpose_kernel(
    const float* __restrict__ W, unsigned short* __restrict__ Wt, int rows, int cols)
{
    __shared__ float t[32][33];
    const int tid = threadIdx.x;
    const int tx = tid & 31, ty = tid >> 5;
    const long r0 = (long)blockIdx.y * 32, c0 = (long)blockIdx.x * 32;
#pragma unroll
    for (int r = 0; r < 32; r += 8)
        t[r + ty][tx] = W[(r0 + r + ty) * (long)cols + c0 + tx];
    __syncthreads();
#pragma unroll
    for (int r = 0; r < 32; r += 8)
        Wt[(c0 + r + ty) * (long)rows + r0 + tx] = f2bf(t[tx][r + ty]);
}

// ---------- host ----------
// Workspace plan (>= 89.2 MB measured-safe):
//   q    : 32 KB
//   pool : attention overlay  Vt 16.8 | Smat 67.1             (= 83.9 MB)
//          MLP overlay        W1t 8.4 | W2t 8.4 | hm 16.8 | hid 67.1/c
//   z (17.8 MB) lives in d_out (33.5 MB) — dead before PV overwrites it.
extern "C" void kernel_launch(void* const* d_in, const int* in_sizes, int n_in,
                              void* d_out, int out_size, void* d_ws, size_t ws_size,
                              hipStream_t stream)
{
    const float* x   = (const float*)d_in[0];
    const float* L   = (const float*)d_in[1];
    const float* W1  = (const float*)d_in[2];
    const float* b1  = (const float*)d_in[3];
    const float* W2  = (const float*)d_in[4];
    const float* b2  = (const float*)d_in[5];
    const float* g1  = (const float*)d_in[6];
    const float* be1 = (const float*)d_in[7];
    const float* g2  = (const float*)d_in[8];
    const float* be2 = (const float*)d_in[9];
    float* out = (float*)d_out;
    unsigned short* z = (unsigned short*)d_out;     // 8192 x 1088 bf16 in d_out

    char* wsp = (char*)d_ws;
    float* q = (float*)wsp;                          // 32 KB
    char* pool = wsp + 32768;
    // attention overlay
    unsigned short* Vt   = (unsigned short*)pool;                      // 4 x 1024 x 2048 bf16
    float*          Smat = (float*)(pool + 16777216);                  // 4 x 2048 x 2048 f32
    // MLP overlay (valid after PV has consumed Vt/Smat)
    unsigned short* W1t = (unsigned short*)pool;                       // 4096 x 1024 bf16
    unsigned short* W2t = (unsigned short*)(pool + 8388608);           // 1024 x 4096 bf16
    unsigned short* hm  = (unsigned short*)(pool + 16777216);          // 8192 x 1024 bf16
    unsigned short* hid = (unsigned short*)(pool + 33554432);          // 8192 x 4096 bf16 (or /2)
    const bool fullMLP = ws_size >= (size_t)32768 + 100663296 + 65536;

    // LN1 -> z[:,0:1024], q = |hn|^2, zero pad cols 1056:1088
    ln_kernel<<<8192, 256, 0, stream>>>(x, g1, be1, z, 1088, q, 1);
    // u = hn@L -> z[:,1024:1056], q += |u|^2
    u_kernel<<<8192, 256, 0, stream>>>(z, L, q);

    // ---- attention, all 4 batches in parallel ----
    transpose_v_kernel<<<dim3(64, 32, 4), 256, 0, stream>>>(z, Vt, (long)1024 * 2048);
    gemm_nt3<256, 0><<<dim3(8, 8, 4), 512, 0, stream>>>(
        z, 1088, (long)2048 * 1088,
        z, 1088, (long)2048 * 1088,
        Smat, 2048, (long)2048 * 2048,
        nullptr, 0, 0, nullptr, 1088);
    softmax_kernel<<<dim3(2048, 4), 256, 0, stream>>>(Smat, q);
    gemm_nt3<128, 1><<<dim3(8, 8, 4), 512, 0, stream>>>(
        (const unsigned short*)Smat, 4096, (long)2048 * 4096,
        Vt, 2048, (long)1024 * 2048,
        out, 1024, (long)2048 * 1024,
        x, 1024, (long)2048 * 1024,
        nullptr, 2048);

    // ---- MLP ----
    cast_transpose_kernel<<<dim3(128, 32), 256, 0, stream>>>(W1, W1t, 1024, 4096);
    cast_transpose_kernel<<<dim3(32, 128), 256, 0, stream>>>(W2, W2t, 4096, 1024);
    ln_kernel<<<8192, 256, 0, stream>>>(out, g2, be2, hm, 1024, nullptr, 0);
    if (fullMLP) {
        gemm_nt3<256, 2><<<dim3(16, 32, 1), 512, 0, stream>>>(
            hm, 1024, 0, W1t, 1024, 0,
            hid, 4096, 0, nullptr, 0, 0, b1, 1024);
        gemm_nt3<128, 3><<<dim3(8, 32, 1), 512, 0, stream>>>(
            hid, 4096, 0, W2t, 4096, 0,
            out, 1024, 0, out, 1024, 0, b2, 4096);
    } else {
        for (int c = 0; c < 2; ++c) {
            const unsigned short* hmc = hm + (size_t)c * 4096 * 1024;
            float* oc = out + (size_t)c * 4096 * 1024;
            gemm_nt3<256, 2><<<dim3(16, 16, 1), 512, 0, stream>>>(
                hmc, 1024, 0, W1t, 1024, 0,
                hid, 4096, 0, nullptr, 0, 0, b1, 1024);
            gemm_nt3<128, 3><<<dim3(8, 16, 1), 512, 0, stream>>>(
                hid, 4096, 0, W2t, 4096, 0,
                oc, 1024, 0, oc, 1024, 0, b2, 4096);
        }
    }
}